// Round 1
// baseline (563.671 us; speedup 1.0000x reference)
//
#include <hip/hip_runtime.h>

// LlamaAttention on MI355X — round 1: bf16-MFMA end-to-end baseline.
// x@Wq/Wk/Wv (fused launch) -> RoPE(+scale into Q) -> flash attn (GQA, causal)
// -> @Wo. All accumulation fp32; operands bf16.

#define B_  2
#define S_  2048
#define E_  2048
#define H_  32
#define KV_ 8
#define HD_ 64

typedef __attribute__((ext_vector_type(8))) short  short8;
typedef __attribute__((ext_vector_type(8))) ushort ushort8;
typedef __attribute__((ext_vector_type(4))) float  f32x4;

__device__ __forceinline__ ushort f2b(float f) {
  uint x = __float_as_uint(f);
  return (ushort)((x + 0x7fffu + ((x >> 16) & 1u)) >> 16);  // RNE
}

__device__ __forceinline__ short8 pack8(uint a, uint b, uint c, uint d) {
  union { uint u[4]; short8 s; } v;
  v.u[0] = a; v.u[1] = b; v.u[2] = c; v.u[3] = d;
  return v.s;
}

// ---------------- cast f32 -> bf16, 8 elems/thread ----------------
__global__ __launch_bounds__(256) void k_cast(const float* __restrict__ in,
                                              ushort* __restrict__ out, int n8) {
  int stride = gridDim.x * 256;
  for (int i = blockIdx.x * 256 + threadIdx.x; i < n8; i += stride) {
    const float4* p = (const float4*)(in + (size_t)i * 8);
    float4 a = p[0], b = p[1];
    ushort8 r;
    r[0]=f2b(a.x); r[1]=f2b(a.y); r[2]=f2b(a.z); r[3]=f2b(a.w);
    r[4]=f2b(b.x); r[5]=f2b(b.y); r[6]=f2b(b.z); r[7]=f2b(b.w);
    *(ushort8*)(out + (size_t)i * 8) = r;
  }
}

// ---------------- bf16 MFMA GEMM core: C[M,N] = A[M,K] @ B[K,N] ----------------
// 128x128 tile, BK=32, 4 waves each 64x64 (4x4 frags of 16x16x32).
// As stride 36 (72B, odd-dword) / Bs stride 132 (264B): frag-read conflicts <=2-way.
__device__ __forceinline__ void gemm_core(ushort As[][36], ushort Bs[][132],
                                          const ushort* __restrict__ A,
                                          const ushort* __restrict__ Bw,
                                          float* __restrict__ C,
                                          int N, int K, int bm, int bn) {
  const int tid  = threadIdx.x;
  const int lane = tid & 63;
  const int w    = tid >> 6;
  const int wr   = w >> 1, wc = w & 1;
  const int fr   = lane & 15, fg = lane >> 4;
  const f32x4 z = {0.f, 0.f, 0.f, 0.f};
  f32x4 acc[4][4];
#pragma unroll
  for (int i = 0; i < 4; ++i)
#pragma unroll
    for (int j = 0; j < 4; ++j) acc[i][j] = z;

  for (int k0 = 0; k0 < K; k0 += 32) {
    __syncthreads();
#pragma unroll
    for (int it = 0; it < 2; ++it) {          // stage A 128x32
      int c = it * 256 + tid;
      int m = c >> 2, kk = (c & 3) << 3;
      uint4 v = *(const uint4*)(A + (size_t)(bm + m) * K + k0 + kk);
      *(uint2*)&As[m][kk]     = make_uint2(v.x, v.y);
      *(uint2*)&As[m][kk + 4] = make_uint2(v.z, v.w);
    }
#pragma unroll
    for (int it = 0; it < 2; ++it) {          // stage B 32x128
      int c = it * 256 + tid;
      int kk = c >> 4, n = (c & 15) << 3;
      uint4 v = *(const uint4*)(Bw + (size_t)(k0 + kk) * N + bn + n);
      *(uint2*)&Bs[kk][n]     = make_uint2(v.x, v.y);
      *(uint2*)&Bs[kk][n + 4] = make_uint2(v.z, v.w);
    }
    __syncthreads();
    short8 af[4], bf[4];
#pragma unroll
    for (int mi = 0; mi < 4; ++mi) {          // A frags: row=fr, k contiguous
      const ushort* p = &As[wr * 64 + mi * 16 + fr][fg * 8];
      uint2 lo = *(const uint2*)p, hi = *(const uint2*)(p + 4);
      af[mi] = pack8(lo.x, lo.y, hi.x, hi.y);
    }
#pragma unroll
    for (int ni = 0; ni < 4; ++ni) {          // B frags: col=fr, k strided (u16 reads)
      int n = wc * 64 + ni * 16 + fr;
      short8 t;
#pragma unroll
      for (int j = 0; j < 8; ++j) t[j] = (short)Bs[fg * 8 + j][n];
      bf[ni] = t;
    }
#pragma unroll
    for (int mi = 0; mi < 4; ++mi)
#pragma unroll
      for (int ni = 0; ni < 4; ++ni)
        acc[mi][ni] = __builtin_amdgcn_mfma_f32_16x16x32_bf16(af[mi], bf[ni], acc[mi][ni], 0, 0, 0);
  }
  // C/D layout: col = lane&15, row = (lane>>4)*4 + r  [m89-verified]
#pragma unroll
  for (int mi = 0; mi < 4; ++mi)
#pragma unroll
    for (int ni = 0; ni < 4; ++ni)
#pragma unroll
      for (int r = 0; r < 4; ++r) {
        int row = bm + wr * 64 + mi * 16 + fg * 4 + r;
        int col = bn + wc * 64 + ni * 16 + fr;
        C[(size_t)row * N + col] = acc[mi][ni][r];
      }
}

// One launch for Q,K,V projections: bx 0..15 -> Q (N=2048), 16..19 -> K, 20..23 -> V.
__global__ __launch_bounds__(256) void k_gemm_qkv(const ushort* __restrict__ xb,
                                                  const ushort* __restrict__ Wqb,
                                                  const ushort* __restrict__ Wkb,
                                                  const ushort* __restrict__ Wvb,
                                                  float* __restrict__ Qt,
                                                  float* __restrict__ Kt,
                                                  float* __restrict__ Vt) {
  __shared__ ushort As[128][36];
  __shared__ ushort Bs[32][132];
  int bx = blockIdx.x;
  int bm = blockIdx.y * 128;
  if (bx < 16)      gemm_core(As, Bs, xb, Wqb, Qt, 2048, 2048, bm, bx * 128);
  else if (bx < 20) gemm_core(As, Bs, xb, Wkb, Kt, 512, 2048, bm, (bx - 16) * 128);
  else              gemm_core(As, Bs, xb, Wvb, Vt, 512, 2048, bm, (bx - 20) * 128);
}

__global__ __launch_bounds__(256) void k_gemm_o(const ushort* __restrict__ A,
                                                const ushort* __restrict__ Bw,
                                                float* __restrict__ C) {
  __shared__ ushort As[128][36];
  __shared__ ushort Bs[32][132];
  gemm_core(As, Bs, A, Bw, C, 2048, 2048, blockIdx.y * 128, blockIdx.x * 128);
}

// ---------------- RoPE + layout to [B][H][S][HD] bf16; scale 1/8 into Q ----------------
__global__ __launch_bounds__(256) void k_rope_q(const float* __restrict__ Qt,
                                                ushort* __restrict__ Qh) {
  int row = blockIdx.x;                 // b*S + s
  int s = row & (S_ - 1), b = row >> 11;
#pragma unroll
  for (int i = 0; i < 4; ++i) {
    int p = threadIdx.x + i * 256;      // pair id 0..1023
    int h = p >> 5, j = p & 31;
    float inv = __expf(-(float)j * 0.2878231366242557f);  // 10000^(-j/32)
    float ang = (float)s * inv;
    float sn, cs; __sincosf(ang, &sn, &cs);
    float2 x12 = *(const float2*)(Qt + (size_t)row * E_ + h * 64 + 2 * j);
    float o1 = (x12.x * cs - x12.y * sn) * 0.125f;
    float o2 = (x12.x * sn + x12.y * cs) * 0.125f;
    size_t o = ((size_t)(b * H_ + h) * S_ + s) * HD_ + 2 * j;
    *(uint*)(Qh + o) = (uint)f2b(o1) | ((uint)f2b(o2) << 16);
  }
}

__global__ __launch_bounds__(256) void k_rope_k(const float* __restrict__ Kt,
                                                ushort* __restrict__ Kh) {
  int row = blockIdx.x;
  int s = row & (S_ - 1), b = row >> 11;
  int p = threadIdx.x;                  // 256 pairs (KV*HD/2)
  int kv = p >> 5, j = p & 31;
  float inv = __expf(-(float)j * 0.2878231366242557f);
  float ang = (float)s * inv;
  float sn, cs; __sincosf(ang, &sn, &cs);
  float2 x12 = *(const float2*)(Kt + (size_t)row * (KV_ * HD_) + kv * 64 + 2 * j);
  float o1 = x12.x * cs - x12.y * sn;
  float o2 = x12.x * sn + x12.y * cs;
  size_t o = ((size_t)(b * KV_ + kv) * S_ + s) * HD_ + 2 * j;
  *(uint*)(Kh + o) = (uint)f2b(o1) | ((uint)f2b(o2) << 16);
}

__global__ __launch_bounds__(256) void k_cast_v(const float* __restrict__ Vt,
                                                ushort* __restrict__ Vh) {
  int i = blockIdx.x * 256 + threadIdx.x;   // 8-elem chunk id
  if (i >= B_ * S_ * KV_ * HD_ / 8) return;
  int c = i * 8;
  int row = c >> 9, cc = c & 511;
  int kv = cc >> 6, d = cc & 63;
  int s = row & (S_ - 1), b = row >> 11;
  const float* src = Vt + (size_t)row * (KV_ * HD_) + cc;
  float4 a = *(const float4*)src, bb = *(const float4*)(src + 4);
  ushort8 r;
  r[0]=f2b(a.x); r[1]=f2b(a.y); r[2]=f2b(a.z); r[3]=f2b(a.w);
  r[4]=f2b(bb.x); r[5]=f2b(bb.y); r[6]=f2b(bb.z); r[7]=f2b(bb.w);
  *(ushort8*)(Vh + (((size_t)(b * KV_ + kv) * S_ + s) * HD_ + d)) = r;
}

// ---------------- flash attention (causal, GQA) ----------------
// grid (S/64, B*H); 4 waves, each owns 16 q rows. K row-major LDS, V transposed
// at staging, P re-layout via LDS. Softmax fp32, 16-lane shfl row-reduce.
__global__ __launch_bounds__(256) void k_attn(const ushort* __restrict__ Qh,
                                              const ushort* __restrict__ Kh,
                                              const ushort* __restrict__ Vh,
                                              ushort* __restrict__ AOb) {
  __shared__ ushort Ks[64][68];
  __shared__ ushort Vs[64][68];   // transposed: Vs[d][k]
  __shared__ ushort Ps[64][68];
  const int qt = blockIdx.x;
  const int bh = blockIdx.y;
  const int b = bh >> 5, h = bh & 31;
  const int kv = h >> 2;
  const ushort* Qb = Qh + (size_t)(b * H_ + h) * S_ * HD_;
  const ushort* Kb = Kh + (size_t)(b * KV_ + kv) * S_ * HD_;
  const ushort* Vb = Vh + (size_t)(b * KV_ + kv) * S_ * HD_;
  const int tid = threadIdx.x, lane = tid & 63, w = tid >> 6;
  const int fr = lane & 15, fg = lane >> 4;

  short8 qf[2];
  {
    int qrow = qt * 64 + w * 16 + fr;
#pragma unroll
    for (int dd = 0; dd < 2; ++dd) {
      uint4 v = *(const uint4*)(Qb + (size_t)qrow * HD_ + dd * 32 + fg * 8);
      qf[dd] = pack8(v.x, v.y, v.z, v.w);
    }
  }
  const f32x4 z = {0.f, 0.f, 0.f, 0.f};
  f32x4 o[4]; float m_run[4], l_run[4];
#pragma unroll
  for (int i = 0; i < 4; ++i) { o[i] = z; m_run[i] = -1e30f; l_run[i] = 0.f; }

  for (int kt = 0; kt <= qt; ++kt) {
    __syncthreads();
#pragma unroll
    for (int it = 0; it < 2; ++it) {   // stage K (row-major) + V (transposed)
      int c = it * 256 + tid;
      int r = c >> 3, col = (c & 7) << 3;
      uint4 vk = *(const uint4*)(Kb + (size_t)(kt * 64 + r) * HD_ + col);
      *(uint2*)&Ks[r][col]     = make_uint2(vk.x, vk.y);
      *(uint2*)&Ks[r][col + 4] = make_uint2(vk.z, vk.w);
      uint4 vv = *(const uint4*)(Vb + (size_t)(kt * 64 + r) * HD_ + col);
      ushort e[8]; *(uint4*)e = vv;
#pragma unroll
      for (int j = 0; j < 8; ++j) Vs[col + j][r] = e[j];
    }
    __syncthreads();

    // S = Q K^T  (A=Q frag, B: col=k, d contiguous = Ks row read)
    f32x4 s[4];
#pragma unroll
    for (int kb = 0; kb < 4; ++kb) {
      s[kb] = z;
#pragma unroll
      for (int dd = 0; dd < 2; ++dd) {
        const ushort* p = &Ks[kb * 16 + fr][dd * 32 + fg * 8];
        uint2 lo = *(const uint2*)p, hi = *(const uint2*)(p + 4);
        short8 kf = pack8(lo.x, lo.y, hi.x, hi.y);
        s[kb] = __builtin_amdgcn_mfma_f32_16x16x32_bf16(qf[dd], kf, s[kb], 0, 0, 0);
      }
    }
    if (kt == qt) {                      // diagonal causal mask
#pragma unroll
      for (int kb = 0; kb < 4; ++kb)
#pragma unroll
        for (int r = 0; r < 4; ++r)
          if (kb * 16 + fr > w * 16 + fg * 4 + r) s[kb][r] = -1e30f;
    }
    // online softmax (rows q = fg*4+r; cols across the 16-lane group)
    float mt[4], sc[4], rs[4];
#pragma unroll
    for (int r = 0; r < 4; ++r)
      mt[r] = fmaxf(fmaxf(s[0][r], s[1][r]), fmaxf(s[2][r], s[3][r]));
#pragma unroll
    for (int off = 1; off < 16; off <<= 1)
#pragma unroll
      for (int r = 0; r < 4; ++r) mt[r] = fmaxf(mt[r], __shfl_xor(mt[r], off));
#pragma unroll
    for (int r = 0; r < 4; ++r) {
      float mn = fmaxf(m_run[r], mt[r]);
      sc[r] = __expf(m_run[r] - mn);
      m_run[r] = mn;
      float su = 0.f;
#pragma unroll
      for (int kb = 0; kb < 4; ++kb) {
        float pv = __expf(s[kb][r] - mn);
        s[kb][r] = pv; su += pv;
      }
      rs[r] = su;
    }
#pragma unroll
    for (int off = 1; off < 16; off <<= 1)
#pragma unroll
      for (int r = 0; r < 4; ++r) rs[r] += __shfl_xor(rs[r], off);
#pragma unroll
    for (int r = 0; r < 4; ++r) l_run[r] = l_run[r] * sc[r] + rs[r];
#pragma unroll
    for (int db = 0; db < 4; ++db)
#pragma unroll
      for (int r = 0; r < 4; ++r) o[db][r] *= sc[r];

    // P: C-layout -> LDS -> A-layout (per-wave strip, no cross-wave barrier)
#pragma unroll
    for (int kb = 0; kb < 4; ++kb)
#pragma unroll
      for (int r = 0; r < 4; ++r)
        Ps[w * 16 + fg * 4 + r][kb * 16 + fr] = f2b(s[kb][r]);
    asm volatile("s_waitcnt lgkmcnt(0)" ::: "memory");

    // O += P V   (A=P frag row=fr; B: col=d, k contiguous = Vs row read)
#pragma unroll
    for (int kk = 0; kk < 2; ++kk) {
      const ushort* pp = &Ps[w * 16 + fr][kk * 32 + fg * 8];
      uint2 plo = *(const uint2*)pp, phi = *(const uint2*)(pp + 4);
      short8 pf = pack8(plo.x, plo.y, phi.x, phi.y);
#pragma unroll
      for (int db = 0; db < 4; ++db) {
        const ushort* vp = &Vs[db * 16 + fr][kk * 32 + fg * 8];
        uint2 vlo = *(const uint2*)vp, vhi = *(const uint2*)(vp + 4);
        short8 vf = pack8(vlo.x, vlo.y, vhi.x, vhi.y);
        o[db] = __builtin_amdgcn_mfma_f32_16x16x32_bf16(pf, vf, o[db], 0, 0, 0);
      }
    }
  }
  // epilogue: AOb[b][s][h*64+d] bf16
#pragma unroll
  for (int db = 0; db < 4; ++db)
#pragma unroll
    for (int r = 0; r < 4; ++r) {
      int qg  = qt * 64 + w * 16 + fg * 4 + r;
      int col = h * HD_ + db * 16 + fr;
      AOb[(size_t)(b * S_ + qg) * E_ + col] = f2b(o[db][r] / l_run[r]);
    }
}

// ---------------- launch ----------------
extern "C" void kernel_launch(void* const* d_in, const int* in_sizes, int n_in,
                              void* d_out, int out_size, void* d_ws, size_t ws_size,
                              hipStream_t stream) {
  const float* x  = (const float*)d_in[0];
  const float* Wq = (const float*)d_in[1];
  const float* Wk = (const float*)d_in[2];
  const float* Wv = (const float*)d_in[3];
  const float* Wo = (const float*)d_in[4];
  float* out = (float*)d_out;

  char* p = (char*)d_ws;
  ushort* xb  = (ushort*)p; p += (size_t)B_ * S_ * E_ * 2;
  ushort* Wqb = (ushort*)p; p += (size_t)E_ * H_ * HD_ * 2;
  ushort* Wkb = (ushort*)p; p += (size_t)E_ * KV_ * HD_ * 2;
  ushort* Wvb = (ushort*)p; p += (size_t)E_ * KV_ * HD_ * 2;
  ushort* Wob = (ushort*)p; p += (size_t)E_ * E_ * 2;
  float*  Qt  = (float*)p;  p += (size_t)B_ * S_ * H_ * HD_ * 4;
  float*  Kt  = (float*)p;  p += (size_t)B_ * S_ * KV_ * HD_ * 4;
  float*  Vt  = (float*)p;  p += (size_t)B_ * S_ * KV_ * HD_ * 4;
  ushort* Qhp = (ushort*)p; p += (size_t)B_ * H_ * S_ * HD_ * 2;
  ushort* Khp = (ushort*)p; p += (size_t)B_ * KV_ * S_ * HD_ * 2;
  ushort* Vhp = (ushort*)p; p += (size_t)B_ * KV_ * S_ * HD_ * 2;
  ushort* AOb = (ushort*)Qt;   // reuse Qt after RoPE consumed it

  k_cast<<<2048, 256, 0, stream>>>(x,  xb,  B_ * S_ * E_ / 8);
  k_cast<<<2048, 256, 0, stream>>>(Wq, Wqb, E_ * H_ * HD_ / 8);
  k_cast<<<512,  256, 0, stream>>>(Wk, Wkb, E_ * KV_ * HD_ / 8);
  k_cast<<<512,  256, 0, stream>>>(Wv, Wvb, E_ * KV_ * HD_ / 8);
  k_cast<<<2048, 256, 0, stream>>>(Wo, Wob, E_ * E_ / 8);

  k_gemm_qkv<<<dim3(24, 32), 256, 0, stream>>>(xb, Wqb, Wkb, Wvb, Qt, Kt, Vt);

  k_rope_q<<<B_ * S_, 256, 0, stream>>>(Qt, Qhp);
  k_rope_k<<<B_ * S_, 256, 0, stream>>>(Kt, Khp);
  k_cast_v<<<B_ * S_ * KV_ * HD_ / 8 / 256, 256, 0, stream>>>(Vt, Vhp);

  k_attn<<<dim3(S_ / 64, B_ * H_), 256, 0, stream>>>(Qhp, Khp, Vhp, AOb);

  k_gemm_o<<<dim3(16, 32), 256, 0, stream>>>(AOb, Wob, out);
}

// Round 2
// 390.247 us; speedup vs baseline: 1.4444x; 1.4444x over previous
//
#include <hip/hip_runtime.h>

// LlamaAttention on MI355X — round 2.
// GEMMs: m97 structure (global_load_lds w16, linear LDS, pre-transposed weights).
// Attention: 128-row q-blocks, global V^T, swizzled gld_lds staging, dbuf overlap.

#define B_  2
#define S_  2048
#define E_  2048
#define H_  32
#define KV_ 8
#define HD_ 64

typedef __attribute__((ext_vector_type(8))) short  short8;
typedef __attribute__((ext_vector_type(8))) ushort ushort8;
typedef __attribute__((ext_vector_type(4))) float  f32x4;

__device__ __forceinline__ ushort f2b(float f) {
  uint x = __float_as_uint(f);
  return (ushort)((x + 0x7fffu + ((x >> 16) & 1u)) >> 16);  // RNE
}

__device__ __forceinline__ short8 pack8(uint4 v) {
  union { uint u[4]; short8 s; } t;
  t.u[0] = v.x; t.u[1] = v.y; t.u[2] = v.z; t.u[3] = v.w;
  return t.s;
}

// async global->LDS, 16B per lane. LDS dest must be wave-uniform base + lane*16.
__device__ __forceinline__ void gload16(const ushort* g, char* l) {
  __builtin_amdgcn_global_load_lds(
      (const __attribute__((address_space(1))) uint*)g,
      (__attribute__((address_space(3))) uint*)l, 16, 0, 0);
}

// ---------------- cast f32 -> bf16 flat ----------------
__global__ __launch_bounds__(256) void k_cast(const float* __restrict__ in,
                                              ushort* __restrict__ out, int n8) {
  int stride = gridDim.x * 256;
  for (int i = blockIdx.x * 256 + threadIdx.x; i < n8; i += stride) {
    const float4* p = (const float4*)(in + (size_t)i * 8);
    float4 a = p[0], b = p[1];
    ushort8 r;
    r[0]=f2b(a.x); r[1]=f2b(a.y); r[2]=f2b(a.z); r[3]=f2b(a.w);
    r[4]=f2b(b.x); r[5]=f2b(b.y); r[6]=f2b(b.z); r[7]=f2b(b.w);
    *(ushort8*)(out + (size_t)i * 8) = r;
  }
}

// ---------------- cast + transpose: in[R][C] f32 -> out[C][R] bf16 ----------------
__global__ __launch_bounds__(256) void k_transpose(const float* __restrict__ in,
                                                   ushort* __restrict__ out,
                                                   int R, int C) {
  __shared__ ushort L[64][68];
  const int c0 = blockIdx.x * 64, r0 = blockIdx.y * 64;
  const int t = threadIdx.x;
  const int row = t >> 2, q4 = (t & 3) * 16;
#pragma unroll
  for (int i = 0; i < 4; ++i) {
    int col = q4 + i * 4;
    float4 v = *(const float4*)(in + (size_t)(r0 + row) * C + c0 + col);
    ushort* p = &L[row][col];
    p[0] = f2b(v.x); p[1] = f2b(v.y); p[2] = f2b(v.z); p[3] = f2b(v.w);
  }
  __syncthreads();
  const int tc = t >> 2;
#pragma unroll
  for (int i = 0; i < 4; ++i) {
    int j = q4 + i * 4;
    ushort4 u;
    u.x = L[j][tc]; u.y = L[j + 1][tc]; u.z = L[j + 2][tc]; u.w = L[j + 3][tc];
    *(ushort4*)(out + (size_t)(c0 + tc) * R + r0 + j) = u;
  }
}

// ---------------- V: f32 [b*S+s][kv*64+d] -> bf16 V^T [bkv][d][s] ----------------
__global__ __launch_bounds__(256) void k_trans_v(const float* __restrict__ Vt,
                                                 ushort* __restrict__ Vh) {
  __shared__ ushort L[64][68];
  const int s0 = blockIdx.x * 64;
  const int bkv = blockIdx.y;
  const int b = bkv >> 3, kv = bkv & 7;
  const int t = threadIdx.x;
  const int row = t >> 2, q4 = (t & 3) * 16;
#pragma unroll
  for (int i = 0; i < 4; ++i) {
    int col = q4 + i * 4;
    float4 v = *(const float4*)(Vt + (size_t)(b * S_ + s0 + row) * (KV_ * HD_) + kv * HD_ + col);
    ushort* p = &L[row][col];
    p[0] = f2b(v.x); p[1] = f2b(v.y); p[2] = f2b(v.z); p[3] = f2b(v.w);
  }
  __syncthreads();
  const int tc = t >> 2;
#pragma unroll
  for (int i = 0; i < 4; ++i) {
    int j = q4 + i * 4;
    ushort4 u;
    u.x = L[j][tc]; u.y = L[j + 1][tc]; u.z = L[j + 2][tc]; u.w = L[j + 3][tc];
    *(ushort4*)(Vh + ((size_t)bkv * HD_ + tc) * S_ + s0 + j) = u;
  }
}

// ---------------- m97-style GEMM: C[M,N] = A[M,K] @ Bt[N,K]^T, fp32 out ----------------
// 128x128 tile, BK=32, 4 waves x (64x64), gld_lds w16, linear LDS (A:0, B:8192).
__device__ __forceinline__ void gemm97(const ushort* __restrict__ A,
                                       const ushort* __restrict__ Bt,
                                       float* __restrict__ C,
                                       int N, int K, int bm, int bn, char* lds) {
  const int tid = threadIdx.x, lane = tid & 63, w = tid >> 6;
  const int wr = w >> 1, wc = w & 1, fr = lane & 15, fg = lane >> 4;
  const f32x4 z = {0.f, 0.f, 0.f, 0.f};
  f32x4 acc[4][4];
#pragma unroll
  for (int i = 0; i < 4; ++i)
#pragma unroll
    for (int j = 0; j < 4; ++j) acc[i][j] = z;

  for (int k0 = 0; k0 < K; k0 += 32) {
    __syncthreads();
#pragma unroll
    for (int i = 0; i < 2; ++i) {
      int slot = (w * 2 + i) * 64 + lane;      // 0..511, 16B each
      int row = slot >> 2, ch = slot & 3;      // 64B rows
      gload16(A  + (size_t)(bm + row) * K + k0 + ch * 8, lds + slot * 16);
      gload16(Bt + (size_t)(bn + row) * K + k0 + ch * 8, lds + 8192 + slot * 16);
    }
    __syncthreads();                           // drains vmcnt(0): tile staged
    short8 af[4], bf[4];
#pragma unroll
    for (int mi = 0; mi < 4; ++mi)
      af[mi] = pack8(*(const uint4*)(lds + (wr * 64 + mi * 16 + fr) * 64 + fg * 16));
#pragma unroll
    for (int ni = 0; ni < 4; ++ni)
      bf[ni] = pack8(*(const uint4*)(lds + 8192 + (wc * 64 + ni * 16 + fr) * 64 + fg * 16));
#pragma unroll
    for (int mi = 0; mi < 4; ++mi)
#pragma unroll
      for (int ni = 0; ni < 4; ++ni)
        acc[mi][ni] = __builtin_amdgcn_mfma_f32_16x16x32_bf16(af[mi], bf[ni], acc[mi][ni], 0, 0, 0);
  }
#pragma unroll
  for (int mi = 0; mi < 4; ++mi)
#pragma unroll
    for (int ni = 0; ni < 4; ++ni)
#pragma unroll
      for (int r = 0; r < 4; ++r) {
        int row = bm + wr * 64 + mi * 16 + fg * 4 + r;
        int col = bn + wc * 64 + ni * 16 + fr;
        C[(size_t)row * N + col] = acc[mi][ni][r];
      }
}

__global__ __launch_bounds__(256) void k_gemm_qkv(const ushort* __restrict__ xb,
                                                  const ushort* __restrict__ WqT,
                                                  const ushort* __restrict__ WkT,
                                                  const ushort* __restrict__ WvT,
                                                  float* __restrict__ Qt,
                                                  float* __restrict__ Kt,
                                                  float* __restrict__ Vt) {
  __shared__ char lds[16384];
  int bx = blockIdx.x, bm = blockIdx.y * 128;
  if (bx < 16)      gemm97(xb, WqT, Qt, 2048, 2048, bm, bx * 128, lds);
  else if (bx < 20) gemm97(xb, WkT, Kt, 512, 2048, bm, (bx - 16) * 128, lds);
  else              gemm97(xb, WvT, Vt, 512, 2048, bm, (bx - 20) * 128, lds);
}

__global__ __launch_bounds__(256) void k_gemm_o(const ushort* __restrict__ A,
                                                const ushort* __restrict__ BtT,
                                                float* __restrict__ C) {
  __shared__ char lds[16384];
  gemm97(A, BtT, C, 2048, 2048, blockIdx.y * 128, blockIdx.x * 128, lds);
}

// ---------------- RoPE (scale 1/8 folded into Q) ----------------
__global__ __launch_bounds__(256) void k_rope_q(const float* __restrict__ Qt,
                                                ushort* __restrict__ Qh) {
  int row = blockIdx.x;                 // b*S + s
  int s = row & (S_ - 1), b = row >> 11;
#pragma unroll
  for (int i = 0; i < 4; ++i) {
    int p = threadIdx.x + i * 256;      // pair id 0..1023
    int h = p >> 5, j = p & 31;
    float inv = __expf(-(float)j * 0.2878231366242557f);  // 10000^(-j/32)
    float ang = (float)s * inv;
    float sn, cs; __sincosf(ang, &sn, &cs);
    float2 x12 = *(const float2*)(Qt + (size_t)row * E_ + h * 64 + 2 * j);
    float o1 = (x12.x * cs - x12.y * sn) * 0.125f;
    float o2 = (x12.x * sn + x12.y * cs) * 0.125f;
    size_t o = ((size_t)(b * H_ + h) * S_ + s) * HD_ + 2 * j;
    *(uint*)(Qh + o) = (uint)f2b(o1) | ((uint)f2b(o2) << 16);
  }
}

__global__ __launch_bounds__(256) void k_rope_k(const float* __restrict__ Kt,
                                                ushort* __restrict__ Kh) {
  int row = blockIdx.x;
  int s = row & (S_ - 1), b = row >> 11;
  int p = threadIdx.x;
  int kv = p >> 5, j = p & 31;
  float inv = __expf(-(float)j * 0.2878231366242557f);
  float ang = (float)s * inv;
  float sn, cs; __sincosf(ang, &sn, &cs);
  float2 x12 = *(const float2*)(Kt + (size_t)row * (KV_ * HD_) + kv * 64 + 2 * j);
  float o1 = x12.x * cs - x12.y * sn;
  float o2 = x12.x * sn + x12.y * cs;
  size_t o = ((size_t)(b * KV_ + kv) * S_ + s) * HD_ + 2 * j;
  *(uint*)(Kh + o) = (uint)f2b(o1) | ((uint)f2b(o2) << 16);
}

// ---------------- flash attention, 128-q-row blocks, dbuf gld_lds staging ----------------
// LDS chunks XOR-swizzled (chunk ^= row&7) via pre-swizzled global source (T21).
__device__ __forceinline__ short8 ldsw(const char* base, int row, int ch) {
  return pack8(*(const uint4*)(base + row * 128 + ((ch ^ (row & 7)) * 16)));
}

__device__ __forceinline__ void att_stage(const ushort* __restrict__ Kb,
                                          const ushort* __restrict__ Vb,
                                          char* klds, int kt, int buf,
                                          int w, int lane) {
#pragma unroll
  for (int i = 0; i < 2; ++i) {
    int slot = (w * 2 + i) * 64 + lane;        // 0..511
    int row = slot >> 3;                       // 0..63 (128B rows)
    int ch = (slot & 7) ^ (row & 7);           // inverse swizzle on global source
    gload16(Kb + (size_t)(kt * 64 + row) * HD_ + ch * 8, klds + buf * 8192 + slot * 16);
    gload16(Vb + (size_t)row * S_ + kt * 64 + ch * 8, klds + 16384 + buf * 8192 + slot * 16);
  }
}

__global__ __launch_bounds__(256, 2) void k_attn(const ushort* __restrict__ Qh,
                                                 const ushort* __restrict__ Kh,
                                                 const ushort* __restrict__ Vh,
                                                 ushort* __restrict__ AOb) {
  __shared__ char klds[32768];     // K dbuf [2][64][64], V^T dbuf [2][64][64]
  __shared__ ushort Ps[128][68];
  const int qt = 15 - (int)(blockIdx.x >> 6);     // heavy tiles first
  const int bh = blockIdx.x & 63;
  const int b = bh >> 5, h = bh & 31, kv = h >> 2;
  const ushort* Qb = Qh + (size_t)(b * H_ + h) * S_ * HD_;
  const ushort* Kb = Kh + (size_t)(b * KV_ + kv) * S_ * HD_;
  const ushort* Vb = Vh + (size_t)(b * KV_ + kv) * HD_ * S_;   // [d][s]
  const int tid = threadIdx.x, lane = tid & 63, w = tid >> 6;
  const int fr = lane & 15, fg = lane >> 4;
  const f32x4 z = {0.f, 0.f, 0.f, 0.f};

  short8 qf[2][2];
#pragma unroll
  for (int mi = 0; mi < 2; ++mi) {
    int qrow = qt * 128 + w * 32 + mi * 16 + fr;
#pragma unroll
    for (int dd = 0; dd < 2; ++dd)
      qf[mi][dd] = pack8(*(const uint4*)(Qb + (size_t)qrow * HD_ + dd * 32 + fg * 8));
  }
  f32x4 o[2][4]; float m_run[2][4], l_run[2][4];
#pragma unroll
  for (int mi = 0; mi < 2; ++mi)
#pragma unroll
    for (int i = 0; i < 4; ++i) { o[mi][i] = z; m_run[mi][i] = -1e30f; l_run[mi][i] = 0.f; }

  const int nt = 2 * qt + 2;
  att_stage(Kb, Vb, klds, 0, 0, w, lane);
  __syncthreads();
  int cur = 0;
  for (int kt = 0; kt < nt; ++kt) {
    if (kt + 1 < nt) att_stage(Kb, Vb, klds, kt + 1, cur ^ 1, w, lane);
    const char* kls = klds + cur * 8192;
    const char* vls = klds + 16384 + cur * 8192;

    // S = Q K^T
    f32x4 s[2][4];
#pragma unroll
    for (int kb = 0; kb < 4; ++kb) {
      short8 kf0 = ldsw(kls, kb * 16 + fr, fg);
      short8 kf1 = ldsw(kls, kb * 16 + fr, 4 + fg);
#pragma unroll
      for (int mi = 0; mi < 2; ++mi) {
        f32x4 t = __builtin_amdgcn_mfma_f32_16x16x32_bf16(qf[mi][0], kf0, z, 0, 0, 0);
        s[mi][kb] = __builtin_amdgcn_mfma_f32_16x16x32_bf16(qf[mi][1], kf1, t, 0, 0, 0);
      }
    }
    if (kt >= 2 * qt) {                        // diagonal tiles: causal mask
#pragma unroll
      for (int mi = 0; mi < 2; ++mi)
#pragma unroll
        for (int kb = 0; kb < 4; ++kb)
#pragma unroll
          for (int r = 0; r < 4; ++r)
            if (kt * 64 + kb * 16 + fr > qt * 128 + w * 32 + mi * 16 + fg * 4 + r)
              s[mi][kb][r] = -1e30f;
    }
    // online softmax (rows owned per lane: q = fg*4+r; cols across 16-lane group)
#pragma unroll
    for (int mi = 0; mi < 2; ++mi) {
      float mt[4], sc[4], su[4];
#pragma unroll
      for (int r = 0; r < 4; ++r)
        mt[r] = fmaxf(fmaxf(s[mi][0][r], s[mi][1][r]), fmaxf(s[mi][2][r], s[mi][3][r]));
#pragma unroll
      for (int off = 1; off < 16; off <<= 1)
#pragma unroll
        for (int r = 0; r < 4; ++r) mt[r] = fmaxf(mt[r], __shfl_xor(mt[r], off));
#pragma unroll
      for (int r = 0; r < 4; ++r) {
        float mn = fmaxf(m_run[mi][r], mt[r]);
        sc[r] = __expf(m_run[mi][r] - mn);
        m_run[mi][r] = mn;
        float acc = 0.f;
#pragma unroll
        for (int kb = 0; kb < 4; ++kb) {
          float pv = __expf(s[mi][kb][r] - mn);
          s[mi][kb][r] = pv; acc += pv;
        }
        su[r] = acc;
      }
#pragma unroll
      for (int off = 1; off < 16; off <<= 1)
#pragma unroll
        for (int r = 0; r < 4; ++r) su[r] += __shfl_xor(su[r], off);
#pragma unroll
      for (int r = 0; r < 4; ++r) l_run[mi][r] = l_run[mi][r] * sc[r] + su[r];
#pragma unroll
      for (int db = 0; db < 4; ++db)
#pragma unroll
        for (int r = 0; r < 4; ++r) o[mi][db][r] *= sc[r];
#pragma unroll
      for (int kb = 0; kb < 4; ++kb)
#pragma unroll
        for (int r = 0; r < 4; ++r)
          Ps[w * 32 + mi * 16 + fg * 4 + r][kb * 16 + fr] = f2b(s[mi][kb][r]);
    }
    asm volatile("s_waitcnt lgkmcnt(0)" ::: "memory");
    __builtin_amdgcn_sched_barrier(0);

    // O += P V (A = P rows, B = V^T rows: k contiguous)
#pragma unroll
    for (int kk = 0; kk < 2; ++kk) {
      short8 pf[2];
#pragma unroll
      for (int mi = 0; mi < 2; ++mi) {
        const ushort* pp = &Ps[w * 32 + mi * 16 + fr][kk * 32 + fg * 8];
        uint2 lo = *(const uint2*)pp, hi = *(const uint2*)(pp + 4);
        pf[mi] = pack8(make_uint4(lo.x, lo.y, hi.x, hi.y));
      }
#pragma unroll
      for (int db = 0; db < 4; ++db) {
        short8 vf = ldsw(vls, db * 16 + fr, kk * 4 + fg);
#pragma unroll
        for (int mi = 0; mi < 2; ++mi)
          o[mi][db] = __builtin_amdgcn_mfma_f32_16x16x32_bf16(pf[mi], vf, o[mi][db], 0, 0, 0);
      }
    }
    __syncthreads();   // drains vmcnt(0): next tile staged; protects dbuf reuse
    cur ^= 1;
  }
#pragma unroll
  for (int mi = 0; mi < 2; ++mi)
#pragma unroll
    for (int db = 0; db < 4; ++db)
#pragma unroll
      for (int r = 0; r < 4; ++r) {
        int qrow = qt * 128 + w * 32 + mi * 16 + fg * 4 + r;
        AOb[(size_t)(b * S_ + qrow) * E_ + h * HD_ + db * 16 + fr] = f2b(o[mi][db][r] / l_run[mi][r]);
      }
}

// ---------------- launch ----------------
extern "C" void kernel_launch(void* const* d_in, const int* in_sizes, int n_in,
                              void* d_out, int out_size, void* d_ws, size_t ws_size,
                              hipStream_t stream) {
  const float* x  = (const float*)d_in[0];
  const float* Wq = (const float*)d_in[1];
  const float* Wk = (const float*)d_in[2];
  const float* Wv = (const float*)d_in[3];
  const float* Wo = (const float*)d_in[4];
  float* out = (float*)d_out;

  char* p = (char*)d_ws;
  ushort* xb  = (ushort*)p; p += (size_t)B_ * S_ * E_ * 2;
  ushort* WqT = (ushort*)p; p += (size_t)E_ * H_ * HD_ * 2;
  ushort* WkT = (ushort*)p; p += (size_t)E_ * KV_ * HD_ * 2;
  ushort* WvT = (ushort*)p; p += (size_t)E_ * KV_ * HD_ * 2;
  ushort* WoT = (ushort*)p; p += (size_t)E_ * E_ * 2;
  float*  Qt  = (float*)p;  p += (size_t)B_ * S_ * H_ * HD_ * 4;
  float*  Kt  = (float*)p;  p += (size_t)B_ * S_ * KV_ * HD_ * 4;
  float*  Vt  = (float*)p;  p += (size_t)B_ * S_ * KV_ * HD_ * 4;
  ushort* Qhp = (ushort*)p; p += (size_t)B_ * H_ * S_ * HD_ * 2;
  ushort* Khp = (ushort*)p; p += (size_t)B_ * KV_ * S_ * HD_ * 2;
  ushort* Vhp = (ushort*)p; p += (size_t)B_ * KV_ * S_ * HD_ * 2;
  ushort* AOb = (ushort*)Qt;   // reuse Qt after RoPE consumed it

  k_cast<<<2048, 256, 0, stream>>>(x, xb, B_ * S_ * E_ / 8);
  k_transpose<<<dim3(32, 32), 256, 0, stream>>>(Wq, WqT, E_, H_ * HD_);
  k_transpose<<<dim3(8, 32),  256, 0, stream>>>(Wk, WkT, E_, KV_ * HD_);
  k_transpose<<<dim3(8, 32),  256, 0, stream>>>(Wv, WvT, E_, KV_ * HD_);
  k_transpose<<<dim3(32, 32), 256, 0, stream>>>(Wo, WoT, E_, E_);

  k_gemm_qkv<<<dim3(24, 32), 256, 0, stream>>>(xb, WqT, WkT, WvT, Qt, Kt, Vt);

  k_rope_q<<<B_ * S_, 256, 0, stream>>>(Qt, Qhp);
  k_rope_k<<<B_ * S_, 256, 0, stream>>>(Kt, Khp);
  k_trans_v<<<dim3(S_ / 64, B_ * KV_), 256, 0, stream>>>(Vt, Vhp);

  k_attn<<<1024, 256, 0, stream>>>(Qhp, Khp, Vhp, AOb);

  k_gemm_o<<<dim3(16, 32), 256, 0, stream>>>(AOb, WoT, out);
}

// Round 4
// 349.509 us; speedup vs baseline: 1.6128x; 1.1166x over previous
//
#include <hip/hip_runtime.h>

// LlamaAttention on MI355X — round 4 (= round 3 + fixed P-fragment assembly).
// QKV GEMM fuses RoPE+bf16+layout epilogues (no fp32 round trip).
// Attention: swapped QK^T (mfma(K,Q)) -> lane-local softmax row, in-register P
// via v_cvt_pk_bf16_f32 + select-AFTER-shuffle bpermute assembly (no P LDS).

#define B_  2
#define S_  2048
#define E_  2048
#define H_  32
#define KV_ 8
#define HD_ 64

typedef __attribute__((ext_vector_type(8))) short  short8;
typedef __attribute__((ext_vector_type(8))) ushort ushort8;
typedef __attribute__((ext_vector_type(4))) float  f32x4;

#define QSCALE 0.1803368801111137f      // (1/8) * log2(e): S in log2 domain
#define LOG2_10K_32 0.4152410058570867f // log2(10000)/32

__device__ __forceinline__ ushort f2b(float f) {
  uint x = __float_as_uint(f);
  return (ushort)((x + 0x7fffu + ((x >> 16) & 1u)) >> 16);  // RNE
}

__device__ __forceinline__ short8 pack8(uint4 v) {
  union { uint u[4]; short8 s; } t;
  t.u[0] = v.x; t.u[1] = v.y; t.u[2] = v.z; t.u[3] = v.w;
  return t.s;
}

__device__ __forceinline__ uint cvtpk(float lo, float hi) {
  uint r;
  asm("v_cvt_pk_bf16_f32 %0, %1, %2" : "=v"(r) : "v"(lo), "v"(hi));
  return r;
}

__device__ __forceinline__ float exp2fast(float x) {
  float r;
  asm("v_exp_f32 %0, %1" : "=v"(r) : "v"(x));
  return r;
}

// async global->LDS, 16B per lane (dest = wave-uniform base + lane*16).
__device__ __forceinline__ void gload16(const ushort* g, char* l) {
  __builtin_amdgcn_global_load_lds(
      (const __attribute__((address_space(1))) uint*)g,
      (__attribute__((address_space(3))) uint*)l, 16, 0, 0);
}

// ---------------- cast f32 -> bf16 flat ----------------
__global__ __launch_bounds__(256) void k_cast(const float* __restrict__ in,
                                              ushort* __restrict__ out, int n8) {
  int stride = gridDim.x * 256;
  for (int i = blockIdx.x * 256 + threadIdx.x; i < n8; i += stride) {
    const float4* p = (const float4*)(in + (size_t)i * 8);
    float4 a = p[0], b = p[1];
    ushort8 r;
    r[0]=f2b(a.x); r[1]=f2b(a.y); r[2]=f2b(a.z); r[3]=f2b(a.w);
    r[4]=f2b(b.x); r[5]=f2b(b.y); r[6]=f2b(b.z); r[7]=f2b(b.w);
    *(ushort8*)(out + (size_t)i * 8) = r;
  }
}

// ---------------- cast + transpose: in[R][C] f32 -> out[C][R] bf16 ----------------
__global__ __launch_bounds__(256) void k_transpose(const float* __restrict__ in,
                                                   ushort* __restrict__ out,
                                                   int R, int C) {
  __shared__ ushort L[64][68];
  const int c0 = blockIdx.x * 64, r0 = blockIdx.y * 64;
  const int t = threadIdx.x;
  const int row = t >> 2, q4 = (t & 3) * 16;
#pragma unroll
  for (int i = 0; i < 4; ++i) {
    int col = q4 + i * 4;
    float4 v = *(const float4*)(in + (size_t)(r0 + row) * C + c0 + col);
    ushort* p = &L[row][col];
    p[0] = f2b(v.x); p[1] = f2b(v.y); p[2] = f2b(v.z); p[3] = f2b(v.w);
  }
  __syncthreads();
  const int tc = t >> 2;
#pragma unroll
  for (int i = 0; i < 4; ++i) {
    int j = q4 + i * 4;
    ushort4 u;
    u.x = L[j][tc]; u.y = L[j + 1][tc]; u.z = L[j + 2][tc]; u.w = L[j + 3][tc];
    *(ushort4*)(out + (size_t)(c0 + tc) * R + r0 + j) = u;
  }
}

// ---------------- m97 GEMM core: acc = A[M,K] @ Bt[N,K]^T (128x128 tile) ----------------
__device__ __forceinline__ void gemm_acc(const ushort* __restrict__ A,
                                         const ushort* __restrict__ Bt,
                                         int K, int bm, int bn, char* lds,
                                         f32x4 acc[4][4]) {
  const int tid = threadIdx.x, lane = tid & 63, w = tid >> 6;
  const int wr = w >> 1, wc = w & 1, fr = lane & 15, fg = lane >> 4;
  const f32x4 z = {0.f, 0.f, 0.f, 0.f};
#pragma unroll
  for (int i = 0; i < 4; ++i)
#pragma unroll
    for (int j = 0; j < 4; ++j) acc[i][j] = z;

  for (int k0 = 0; k0 < K; k0 += 32) {
    __syncthreads();
#pragma unroll
    for (int i = 0; i < 2; ++i) {
      int slot = (w * 2 + i) * 64 + lane;      // 0..511, 16B each
      int row = slot >> 2, ch = slot & 3;      // 64B rows
      gload16(A  + (size_t)(bm + row) * K + k0 + ch * 8, lds + slot * 16);
      gload16(Bt + (size_t)(bn + row) * K + k0 + ch * 8, lds + 8192 + slot * 16);
    }
    __syncthreads();                           // drains vmcnt(0): tile staged
    short8 af[4], bf[4];
#pragma unroll
    for (int mi = 0; mi < 4; ++mi)
      af[mi] = pack8(*(const uint4*)(lds + (wr * 64 + mi * 16 + fr) * 64 + fg * 16));
#pragma unroll
    for (int ni = 0; ni < 4; ++ni)
      bf[ni] = pack8(*(const uint4*)(lds + 8192 + (wc * 64 + ni * 16 + fr) * 64 + fg * 16));
#pragma unroll
    for (int mi = 0; mi < 4; ++mi)
#pragma unroll
      for (int ni = 0; ni < 4; ++ni)
        acc[mi][ni] = __builtin_amdgcn_mfma_f32_16x16x32_bf16(af[mi], bf[ni], acc[mi][ni], 0, 0, 0);
  }
}

// QKV projections with fused epilogues:
//  bx<16: Q -> RoPE*QSCALE -> Qh[b,h,s,d] bf16
//  16..19: K -> RoPE       -> Kh[b,kv,s,d] bf16
//  20..23: V ->            -> Vh[bkv,d,s]  bf16 (transposed)
__global__ __launch_bounds__(256) void k_gemm_qkv(const ushort* __restrict__ xb,
                                                  const ushort* __restrict__ WqT,
                                                  const ushort* __restrict__ WkT,
                                                  const ushort* __restrict__ WvT,
                                                  ushort* __restrict__ Qh,
                                                  ushort* __restrict__ Kh,
                                                  ushort* __restrict__ Vh) {
  __shared__ char lds[16384];
  const int bx = blockIdx.x, bm = blockIdx.y * 128;
  const int tid = threadIdx.x, lane = tid & 63, w = tid >> 6;
  const int wr = w >> 1, wc = w & 1, fr = lane & 15, fg = lane >> 4;
  f32x4 acc[4][4];

  if (bx < 16) {          // ---- Q ----
    gemm_acc(xb, WqT, 2048, bm, bx * 128, lds, acc);
#pragma unroll
    for (int ni = 0; ni < 4; ++ni) {
      int n = bx * 128 + wc * 64 + ni * 16 + fr;
      int h = n >> 6, d = n & 63, j = d >> 1;
      float ifr = exp2fast(-(float)j * LOG2_10K_32);
      bool ev = !(d & 1);
#pragma unroll
      for (int mi = 0; mi < 4; ++mi)
#pragma unroll
        for (int r = 0; r < 4; ++r) {
          int m = bm + wr * 64 + mi * 16 + fg * 4 + r;
          int srow = m & (S_ - 1), bb = m >> 11;
          float sn, cs; __sincosf((float)srow * ifr, &sn, &cs);
          float own = acc[mi][ni][r];
          float part = __shfl_xor(own, 1);
          float o = ev ? (own * cs - part * sn) : (part * sn + own * cs);
          Qh[((size_t)(bb * H_ + h) * S_ + srow) * HD_ + d] = f2b(o * QSCALE);
        }
    }
  } else if (bx < 20) {   // ---- K ----
    gemm_acc(xb, WkT, 2048, bm, (bx - 16) * 128, lds, acc);
#pragma unroll
    for (int ni = 0; ni < 4; ++ni) {
      int n = (bx - 16) * 128 + wc * 64 + ni * 16 + fr;
      int kv = n >> 6, d = n & 63, j = d >> 1;
      float ifr = exp2fast(-(float)j * LOG2_10K_32);
      bool ev = !(d & 1);
#pragma unroll
      for (int mi = 0; mi < 4; ++mi)
#pragma unroll
        for (int r = 0; r < 4; ++r) {
          int m = bm + wr * 64 + mi * 16 + fg * 4 + r;
          int srow = m & (S_ - 1), bb = m >> 11;
          float sn, cs; __sincosf((float)srow * ifr, &sn, &cs);
          float own = acc[mi][ni][r];
          float part = __shfl_xor(own, 1);
          float o = ev ? (own * cs - part * sn) : (part * sn + own * cs);
          Kh[((size_t)(bb * KV_ + kv) * S_ + srow) * HD_ + d] = f2b(o);
        }
    }
  } else {                // ---- V (transposed out) ----
    gemm_acc(xb, WvT, 2048, bm, (bx - 20) * 128, lds, acc);
#pragma unroll
    for (int ni = 0; ni < 4; ++ni) {
      int n = (bx - 20) * 128 + wc * 64 + ni * 16 + fr;
      int kv = n >> 6, d = n & 63;
#pragma unroll
      for (int mi = 0; mi < 4; ++mi) {
        int m0 = bm + wr * 64 + mi * 16 + fg * 4;
        int s0 = m0 & (S_ - 1), bb = m0 >> 11;
        ushort4 u;
        u.x = f2b(acc[mi][ni][0]); u.y = f2b(acc[mi][ni][1]);
        u.z = f2b(acc[mi][ni][2]); u.w = f2b(acc[mi][ni][3]);
        *(ushort4*)(Vh + ((size_t)((bb * KV_ + kv) * HD_ + d)) * S_ + s0) = u;
      }
    }
  }
}

// O-projection: fp32 out
__global__ __launch_bounds__(256) void k_gemm_o(const ushort* __restrict__ A,
                                                const ushort* __restrict__ BtT,
                                                float* __restrict__ C) {
  __shared__ char lds[16384];
  const int bm = blockIdx.y * 128, bn = blockIdx.x * 128;
  const int tid = threadIdx.x, lane = tid & 63, w = tid >> 6;
  const int wr = w >> 1, wc = w & 1, fr = lane & 15, fg = lane >> 4;
  f32x4 acc[4][4];
  gemm_acc(A, BtT, 2048, bm, bn, lds, acc);
#pragma unroll
  for (int mi = 0; mi < 4; ++mi)
#pragma unroll
    for (int ni = 0; ni < 4; ++ni)
#pragma unroll
      for (int r = 0; r < 4; ++r) {
        int row = bm + wr * 64 + mi * 16 + fg * 4 + r;
        int col = bn + wc * 64 + ni * 16 + fr;
        C[(size_t)row * 2048 + col] = acc[mi][ni][r];
      }
}

// ---------------- flash attention: swapped QK^T, in-register P ----------------
__device__ __forceinline__ short8 ldsw(const char* base, int row, int ch) {
  return pack8(*(const uint4*)(base + row * 128 + ((ch ^ (row & 7)) * 16)));
}

__device__ __forceinline__ void att_stage(const ushort* __restrict__ Kb,
                                          const ushort* __restrict__ Vb,
                                          char* klds, int kt, int buf,
                                          int w, int lane) {
#pragma unroll
  for (int i = 0; i < 2; ++i) {
    int slot = (w * 2 + i) * 64 + lane;        // 0..511
    int row = slot >> 3;                       // 0..63 (128B rows)
    int ch = (slot & 7) ^ (row & 7);           // inverse swizzle on global source
    gload16(Kb + (size_t)(kt * 64 + row) * HD_ + ch * 8, klds + buf * 8192 + slot * 16);
    gload16(Vb + (size_t)row * S_ + kt * 64 + ch * 8, klds + 16384 + buf * 8192 + slot * 16);
  }
}

__global__ __launch_bounds__(256, 3) void k_attn(const ushort* __restrict__ Qh,
                                                 const ushort* __restrict__ Kh,
                                                 const ushort* __restrict__ Vh,
                                                 ushort* __restrict__ AOb) {
  __shared__ char klds[32768];     // K dbuf [2][64][64], V^T dbuf [2][64][64]
  const int qt = 15 - (int)(blockIdx.x >> 6);     // heavy tiles first
  const int bh = blockIdx.x & 63;
  const int b = bh >> 5, h = bh & 31, kv = h >> 2;
  const ushort* Qb = Qh + (size_t)(b * H_ + h) * S_ * HD_;
  const ushort* Kb = Kh + (size_t)(b * KV_ + kv) * S_ * HD_;
  const ushort* Vb = Vh + (size_t)(b * KV_ + kv) * HD_ * S_;   // [d][s]
  const int tid = threadIdx.x, lane = tid & 63, w = tid >> 6;
  const int fr = lane & 15, fg = lane >> 4;
  const f32x4 z = {0.f, 0.f, 0.f, 0.f};
  const int qbase = qt * 128 + w * 32;

  short8 qf[2][2];       // B-operand: lane holds Q[q=fr][d=fg*8..]
#pragma unroll
  for (int mi = 0; mi < 2; ++mi) {
    int qrow = qbase + mi * 16 + fr;
#pragma unroll
    for (int dd = 0; dd < 2; ++dd)
      qf[mi][dd] = pack8(*(const uint4*)(Qb + (size_t)qrow * HD_ + dd * 32 + fg * 8));
  }
  f32x4 o[2][4];         // O[q=mi*16+fg*4+r][d=db*16+fr]
  float m_run[2], l_run[2];   // per lane: q = mi*16+fr
#pragma unroll
  for (int mi = 0; mi < 2; ++mi) {
    m_run[mi] = -1e30f; l_run[mi] = 0.f;
#pragma unroll
    for (int db = 0; db < 4; ++db) o[mi][db] = z;
  }

  const int nt = 2 * qt + 2;
  att_stage(Kb, Vb, klds, 0, 0, w, lane);
  __syncthreads();
  int cur = 0;
  for (int kt = 0; kt < nt; ++kt) {
    if (kt + 1 < nt) att_stage(Kb, Vb, klds, kt + 1, cur ^ 1, w, lane);
    const char* kls = klds + cur * 8192;
    const char* vls = klds + 16384 + cur * 8192;

    // S^T = K Q^T : C col=q=fr, row k = kb*16 + fg*4 + r  (log2 domain)
    f32x4 s[2][4];
    __builtin_amdgcn_s_setprio(1);
#pragma unroll
    for (int kb = 0; kb < 4; ++kb) {
      short8 kf0 = ldsw(kls, kb * 16 + fr, fg);
      short8 kf1 = ldsw(kls, kb * 16 + fr, 4 + fg);
#pragma unroll
      for (int mi = 0; mi < 2; ++mi) {
        f32x4 t = __builtin_amdgcn_mfma_f32_16x16x32_bf16(kf0, qf[mi][0], z, 0, 0, 0);
        s[mi][kb] = __builtin_amdgcn_mfma_f32_16x16x32_bf16(kf1, qf[mi][1], t, 0, 0, 0);
      }
    }
    __builtin_amdgcn_s_setprio(0);
    if (kt >= 2 * qt) {                        // diagonal: causal mask
#pragma unroll
      for (int mi = 0; mi < 2; ++mi)
#pragma unroll
        for (int kb = 0; kb < 4; ++kb)
#pragma unroll
          for (int r = 0; r < 4; ++r)
            if (kt * 64 + kb * 16 + fg * 4 + r > qbase + mi * 16 + fr)
              s[mi][kb][r] = -1e30f;
    }

    short8 pa[2][2];     // PV A-operand: P[q=fr][k=kk*32+fg*8..]
#pragma unroll
    for (int mi = 0; mi < 2; ++mi) {
      // row max over lane-local 16 + cross-fg reduce
      float mt = s[mi][0][0];
#pragma unroll
      for (int kb = 0; kb < 4; ++kb)
#pragma unroll
        for (int r = 0; r < 4; ++r) mt = fmaxf(mt, s[mi][kb][r]);
      mt = fmaxf(mt, __shfl_xor(mt, 16));
      mt = fmaxf(mt, __shfl_xor(mt, 32));
      float mn = fmaxf(m_run[mi], mt);
      float sc = exp2fast(m_run[mi] - mn);
      m_run[mi] = mn;
      float su = 0.f;
#pragma unroll
      for (int kb = 0; kb < 4; ++kb)
#pragma unroll
        for (int r = 0; r < 4; ++r) {
          float pv = exp2fast(s[mi][kb][r] - mn);
          s[mi][kb][r] = pv; su += pv;
        }
      su += __shfl_xor(su, 16);
      su += __shfl_xor(su, 32);
      l_run[mi] = l_run[mi] * sc + su;
      // rescale O rows (q = fg*4+r lives on lane with fr = fg*4+r)
#pragma unroll
      for (int r = 0; r < 4; ++r) {
        float scb = __shfl(sc, fg * 16 + fg * 4 + r);
#pragma unroll
        for (int db = 0; db < 4; ++db) o[mi][db][r] *= scb;
      }
      // pack P -> bf16 pairs
      uint P01[4], P23[4];
#pragma unroll
      for (int kb = 0; kb < 4; ++kb) {
        P01[kb] = cvtpk(s[mi][kb][0], s[mi][kb][1]);
        P23[kb] = cvtpk(s[mi][kb][2], s[mi][kb][3]);
      }
      // assemble A-fragments: dword i of pa[kk] = P-pair at k = 32kk + 8fg + 2i.
      // source lane fg_s = (2fg + (i>>1))&3, register kb = 2kk + (fg>>1) -> must
      // select AFTER the shuffle (shfl transmits the SOURCE lane's value).
#pragma unroll
      for (int kk = 0; kk < 2; ++kk) {
        const int s0l = (((2 * fg) & 3) << 4) | fr;       // for i = 0,1
        const int s1l = (((2 * fg + 1) & 3) << 4) | fr;   // for i = 2,3
        uint a0 = (uint)__shfl((int)P01[2 * kk],     s0l);
        uint b0 = (uint)__shfl((int)P01[2 * kk + 1], s0l);
        uint a1 = (uint)__shfl((int)P23[2 * kk],     s0l);
        uint b1 = (uint)__shfl((int)P23[2 * kk + 1], s0l);
        uint a2 = (uint)__shfl((int)P01[2 * kk],     s1l);
        uint b2 = (uint)__shfl((int)P01[2 * kk + 1], s1l);
        uint a3 = (uint)__shfl((int)P23[2 * kk],     s1l);
        uint b3 = (uint)__shfl((int)P23[2 * kk + 1], s1l);
        bool hb = (fg & 2) != 0;                          // kb offset = fg>>1
        pa[mi][kk] = pack8(make_uint4(hb ? b0 : a0, hb ? b1 : a1,
                                      hb ? b2 : a2, hb ? b3 : a3));
      }
    }

    // O += P V : B-operand V[k][d=fr] from V^T rows (k contiguous)
    __builtin_amdgcn_s_setprio(1);
#pragma unroll
    for (int kk = 0; kk < 2; ++kk)
#pragma unroll
      for (int db = 0; db < 4; ++db) {
        short8 vf = ldsw(vls, db * 16 + fr, kk * 4 + fg);
#pragma unroll
        for (int mi = 0; mi < 2; ++mi)
          o[mi][db] = __builtin_amdgcn_mfma_f32_16x16x32_bf16(pa[mi][kk], vf, o[mi][db], 0, 0, 0);
      }
    __builtin_amdgcn_s_setprio(0);
    __syncthreads();   // drains vmcnt(0): next tile staged; protects dbuf
    cur ^= 1;
  }
  // epilogue: normalize rows, write AOb[b*S+q][h*64+d]
#pragma unroll
  for (int mi = 0; mi < 2; ++mi) {
    float linv = 1.f / l_run[mi];
#pragma unroll
    for (int r = 0; r < 4; ++r) {
      float lb = __shfl(linv, fg * 16 + fg * 4 + r);
      int qrow = qbase + mi * 16 + fg * 4 + r;
#pragma unroll
      for (int db = 0; db < 4; ++db)
        AOb[(size_t)(b * S_ + qrow) * E_ + h * HD_ + db * 16 + fr] = f2b(o[mi][db][r] * lb);
    }
  }
}

// ---------------- launch ----------------
extern "C" void kernel_launch(void* const* d_in, const int* in_sizes, int n_in,
                              void* d_out, int out_size, void* d_ws, size_t ws_size,
                              hipStream_t stream) {
  const float* x  = (const float*)d_in[0];
  const float* Wq = (const float*)d_in[1];
  const float* Wk = (const float*)d_in[2];
  const float* Wv = (const float*)d_in[3];
  const float* Wo = (const float*)d_in[4];
  float* out = (float*)d_out;

  char* p = (char*)d_ws;
  ushort* xb  = (ushort*)p; p += (size_t)B_ * S_ * E_ * 2;
  ushort* WqT = (ushort*)p; p += (size_t)E_ * H_ * HD_ * 2;
  ushort* WkT = (ushort*)p; p += (size_t)E_ * KV_ * HD_ * 2;
  ushort* WvT = (ushort*)p; p += (size_t)E_ * KV_ * HD_ * 2;
  ushort* WoT = (ushort*)p; p += (size_t)E_ * E_ * 2;
  ushort* Qhp = (ushort*)p; p += (size_t)B_ * H_ * S_ * HD_ * 2;
  ushort* Khp = (ushort*)p; p += (size_t)B_ * KV_ * S_ * HD_ * 2;
  ushort* Vhp = (ushort*)p; p += (size_t)B_ * KV_ * S_ * HD_ * 2;
  ushort* AOb = (ushort*)p; p += (size_t)B_ * S_ * E_ * 2;

  k_cast<<<2048, 256, 0, stream>>>(x, xb, B_ * S_ * E_ / 8);
  k_transpose<<<dim3(32, 32), 256, 0, stream>>>(Wq, WqT, E_, H_ * HD_);
  k_transpose<<<dim3(8, 32),  256, 0, stream>>>(Wk, WkT, E_, KV_ * HD_);
  k_transpose<<<dim3(8, 32),  256, 0, stream>>>(Wv, WvT, E_, KV_ * HD_);
  k_transpose<<<dim3(32, 32), 256, 0, stream>>>(Wo, WoT, E_, E_);

  k_gemm_qkv<<<dim3(24, 32), 256, 0, stream>>>(xb, WqT, WkT, WvT, Qhp, Khp, Vhp);

  k_attn<<<1024, 256, 0, stream>>>(Qhp, Khp, Vhp, AOb);

  k_gemm_o<<<dim3(16, 32), 256, 0, stream>>>(AOb, WoT, out);
}

// Round 5
// 309.743 us; speedup vs baseline: 1.8198x; 1.1284x over previous
//
#include <hip/hip_runtime.h>

// LlamaAttention on MI355X — round 5 (= round 4 + dbuf-prefetch GEMM core).
// GEMMs now use the k_attn-proven 1-barrier/K-step double-buffer protocol:
// issue stage(t+1) -> compute(t) -> barrier (drain lands after compute).

#define B_  2
#define S_  2048
#define E_  2048
#define H_  32
#define KV_ 8
#define HD_ 64

typedef __attribute__((ext_vector_type(8))) short  short8;
typedef __attribute__((ext_vector_type(8))) ushort ushort8;
typedef __attribute__((ext_vector_type(4))) float  f32x4;

#define QSCALE 0.1803368801111137f      // (1/8) * log2(e): S in log2 domain
#define LOG2_10K_32 0.4152410058570867f // log2(10000)/32

__device__ __forceinline__ ushort f2b(float f) {
  uint x = __float_as_uint(f);
  return (ushort)((x + 0x7fffu + ((x >> 16) & 1u)) >> 16);  // RNE
}

__device__ __forceinline__ short8 pack8(uint4 v) {
  union { uint u[4]; short8 s; } t;
  t.u[0] = v.x; t.u[1] = v.y; t.u[2] = v.z; t.u[3] = v.w;
  return t.s;
}

__device__ __forceinline__ uint cvtpk(float lo, float hi) {
  uint r;
  asm("v_cvt_pk_bf16_f32 %0, %1, %2" : "=v"(r) : "v"(lo), "v"(hi));
  return r;
}

__device__ __forceinline__ float exp2fast(float x) {
  float r;
  asm("v_exp_f32 %0, %1" : "=v"(r) : "v"(x));
  return r;
}

// async global->LDS, 16B per lane (dest = wave-uniform base + lane*16).
__device__ __forceinline__ void gload16(const ushort* g, char* l) {
  __builtin_amdgcn_global_load_lds(
      (const __attribute__((address_space(1))) uint*)g,
      (__attribute__((address_space(3))) uint*)l, 16, 0, 0);
}

// ---------------- cast f32 -> bf16 flat ----------------
__global__ __launch_bounds__(256) void k_cast(const float* __restrict__ in,
                                              ushort* __restrict__ out, int n8) {
  int stride = gridDim.x * 256;
  for (int i = blockIdx.x * 256 + threadIdx.x; i < n8; i += stride) {
    const float4* p = (const float4*)(in + (size_t)i * 8);
    float4 a = p[0], b = p[1];
    ushort8 r;
    r[0]=f2b(a.x); r[1]=f2b(a.y); r[2]=f2b(a.z); r[3]=f2b(a.w);
    r[4]=f2b(b.x); r[5]=f2b(b.y); r[6]=f2b(b.z); r[7]=f2b(b.w);
    *(ushort8*)(out + (size_t)i * 8) = r;
  }
}

// ---------------- cast + transpose: in[R][C] f32 -> out[C][R] bf16 ----------------
__global__ __launch_bounds__(256) void k_transpose(const float* __restrict__ in,
                                                   ushort* __restrict__ out,
                                                   int R, int C) {
  __shared__ ushort L[64][68];
  const int c0 = blockIdx.x * 64, r0 = blockIdx.y * 64;
  const int t = threadIdx.x;
  const int row = t >> 2, q4 = (t & 3) * 16;
#pragma unroll
  for (int i = 0; i < 4; ++i) {
    int col = q4 + i * 4;
    float4 v = *(const float4*)(in + (size_t)(r0 + row) * C + c0 + col);
    ushort* p = &L[row][col];
    p[0] = f2b(v.x); p[1] = f2b(v.y); p[2] = f2b(v.z); p[3] = f2b(v.w);
  }
  __syncthreads();
  const int tc = t >> 2;
#pragma unroll
  for (int i = 0; i < 4; ++i) {
    int j = q4 + i * 4;
    ushort4 u;
    u.x = L[j][tc]; u.y = L[j + 1][tc]; u.z = L[j + 2][tc]; u.w = L[j + 3][tc];
    *(ushort4*)(out + (size_t)(c0 + tc) * R + r0 + j) = u;
  }
}

// ---------------- dbuf GEMM core: acc = A[M,K] @ Bt[N,K]^T (128x128 tile) ----------------
// LDS 32 KB: [buf][A 8K | B 8K]. One barrier per K-step; stage(t+1) issued
// before compute(t) so the vmcnt(0) drain at the barrier lands after compute.
__device__ __forceinline__ void gstage(const ushort* __restrict__ A,
                                       const ushort* __restrict__ Bt,
                                       int K, int bm, int bn, int k0,
                                       char* base, int w, int lane) {
#pragma unroll
  for (int i = 0; i < 2; ++i) {
    int slot = (w * 2 + i) * 64 + lane;        // 0..511, 16B each
    int row = slot >> 2, ch = slot & 3;        // 64B rows
    gload16(A  + (size_t)(bm + row) * K + k0 + ch * 8, base + slot * 16);
    gload16(Bt + (size_t)(bn + row) * K + k0 + ch * 8, base + 8192 + slot * 16);
  }
}

__device__ __forceinline__ void gemm_acc(const ushort* __restrict__ A,
                                         const ushort* __restrict__ Bt,
                                         int K, int bm, int bn, char* lds,
                                         f32x4 acc[4][4]) {
  const int tid = threadIdx.x, lane = tid & 63, w = tid >> 6;
  const int wr = w >> 1, wc = w & 1, fr = lane & 15, fg = lane >> 4;
  const f32x4 z = {0.f, 0.f, 0.f, 0.f};
#pragma unroll
  for (int i = 0; i < 4; ++i)
#pragma unroll
    for (int j = 0; j < 4; ++j) acc[i][j] = z;

  gstage(A, Bt, K, bm, bn, 0, lds, w, lane);
  __syncthreads();                             // drains vmcnt(0): buf0 staged
  int cur = 0;
  for (int k0 = 0; k0 < K; k0 += 32) {
    if (k0 + 32 < K)
      gstage(A, Bt, K, bm, bn, k0 + 32, lds + (cur ^ 1) * 16384, w, lane);
    const char* ab = lds + cur * 16384;
    const char* bb = ab + 8192;
    short8 af[4], bf[4];
#pragma unroll
    for (int mi = 0; mi < 4; ++mi)
      af[mi] = pack8(*(const uint4*)(ab + (wr * 64 + mi * 16 + fr) * 64 + fg * 16));
#pragma unroll
    for (int ni = 0; ni < 4; ++ni)
      bf[ni] = pack8(*(const uint4*)(bb + (wc * 64 + ni * 16 + fr) * 64 + fg * 16));
#pragma unroll
    for (int mi = 0; mi < 4; ++mi)
#pragma unroll
      for (int ni = 0; ni < 4; ++ni)
        acc[mi][ni] = __builtin_amdgcn_mfma_f32_16x16x32_bf16(af[mi], bf[ni], acc[mi][ni], 0, 0, 0);
    __syncthreads();   // drain: next buf staged; all waves done reading cur
    cur ^= 1;
  }
}

// QKV projections with fused epilogues:
//  bx<16: Q -> RoPE*QSCALE -> Qh[b,h,s,d] bf16
//  16..19: K -> RoPE       -> Kh[b,kv,s,d] bf16
//  20..23: V ->            -> Vh[bkv,d,s]  bf16 (transposed)
__global__ __launch_bounds__(256) void k_gemm_qkv(const ushort* __restrict__ xb,
                                                  const ushort* __restrict__ WqT,
                                                  const ushort* __restrict__ WkT,
                                                  const ushort* __restrict__ WvT,
                                                  ushort* __restrict__ Qh,
                                                  ushort* __restrict__ Kh,
                                                  ushort* __restrict__ Vh) {
  __shared__ char lds[32768];
  const int bx = blockIdx.x, bm = blockIdx.y * 128;
  const int tid = threadIdx.x, lane = tid & 63, w = tid >> 6;
  const int wr = w >> 1, wc = w & 1, fr = lane & 15, fg = lane >> 4;
  f32x4 acc[4][4];

  if (bx < 16) {          // ---- Q ----
    gemm_acc(xb, WqT, 2048, bm, bx * 128, lds, acc);
#pragma unroll
    for (int ni = 0; ni < 4; ++ni) {
      int n = bx * 128 + wc * 64 + ni * 16 + fr;
      int h = n >> 6, d = n & 63, j = d >> 1;
      float ifr = exp2fast(-(float)j * LOG2_10K_32);
      bool ev = !(d & 1);
#pragma unroll
      for (int mi = 0; mi < 4; ++mi)
#pragma unroll
        for (int r = 0; r < 4; ++r) {
          int m = bm + wr * 64 + mi * 16 + fg * 4 + r;
          int srow = m & (S_ - 1), bb = m >> 11;
          float sn, cs; __sincosf((float)srow * ifr, &sn, &cs);
          float own = acc[mi][ni][r];
          float part = __shfl_xor(own, 1);
          float o = ev ? (own * cs - part * sn) : (part * sn + own * cs);
          Qh[((size_t)(bb * H_ + h) * S_ + srow) * HD_ + d] = f2b(o * QSCALE);
        }
    }
  } else if (bx < 20) {   // ---- K ----
    gemm_acc(xb, WkT, 2048, bm, (bx - 16) * 128, lds, acc);
#pragma unroll
    for (int ni = 0; ni < 4; ++ni) {
      int n = (bx - 16) * 128 + wc * 64 + ni * 16 + fr;
      int kv = n >> 6, d = n & 63, j = d >> 1;
      float ifr = exp2fast(-(float)j * LOG2_10K_32);
      bool ev = !(d & 1);
#pragma unroll
      for (int mi = 0; mi < 4; ++mi)
#pragma unroll
        for (int r = 0; r < 4; ++r) {
          int m = bm + wr * 64 + mi * 16 + fg * 4 + r;
          int srow = m & (S_ - 1), bb = m >> 11;
          float sn, cs; __sincosf((float)srow * ifr, &sn, &cs);
          float own = acc[mi][ni][r];
          float part = __shfl_xor(own, 1);
          float o = ev ? (own * cs - part * sn) : (part * sn + own * cs);
          Kh[((size_t)(bb * KV_ + kv) * S_ + srow) * HD_ + d] = f2b(o);
        }
    }
  } else {                // ---- V (transposed out) ----
    gemm_acc(xb, WvT, 2048, bm, (bx - 20) * 128, lds, acc);
#pragma unroll
    for (int ni = 0; ni < 4; ++ni) {
      int n = (bx - 20) * 128 + wc * 64 + ni * 16 + fr;
      int kv = n >> 6, d = n & 63;
#pragma unroll
      for (int mi = 0; mi < 4; ++mi) {
        int m0 = bm + wr * 64 + mi * 16 + fg * 4;
        int s0 = m0 & (S_ - 1), bb = m0 >> 11;
        ushort4 u;
        u.x = f2b(acc[mi][ni][0]); u.y = f2b(acc[mi][ni][1]);
        u.z = f2b(acc[mi][ni][2]); u.w = f2b(acc[mi][ni][3]);
        *(ushort4*)(Vh + ((size_t)((bb * KV_ + kv) * HD_ + d)) * S_ + s0) = u;
      }
    }
  }
}

// O-projection: fp32 out
__global__ __launch_bounds__(256) void k_gemm_o(const ushort* __restrict__ A,
                                                const ushort* __restrict__ BtT,
                                                float* __restrict__ C) {
  __shared__ char lds[32768];
  const int bm = blockIdx.y * 128, bn = blockIdx.x * 128;
  const int tid = threadIdx.x, lane = tid & 63, w = tid >> 6;
  const int wr = w >> 1, wc = w & 1, fr = lane & 15, fg = lane >> 4;
  f32x4 acc[4][4];
  gemm_acc(A, BtT, 2048, bm, bn, lds, acc);
#pragma unroll
  for (int mi = 0; mi < 4; ++mi)
#pragma unroll
    for (int ni = 0; ni < 4; ++ni)
#pragma unroll
      for (int r = 0; r < 4; ++r) {
        int row = bm + wr * 64 + mi * 16 + fg * 4 + r;
        int col = bn + wc * 64 + ni * 16 + fr;
        C[(size_t)row * 2048 + col] = acc[mi][ni][r];
      }
}

// ---------------- flash attention: swapped QK^T, in-register P ----------------
__device__ __forceinline__ short8 ldsw(const char* base, int row, int ch) {
  return pack8(*(const uint4*)(base + row * 128 + ((ch ^ (row & 7)) * 16)));
}

__device__ __forceinline__ void att_stage(const ushort* __restrict__ Kb,
                                          const ushort* __restrict__ Vb,
                                          char* klds, int kt, int buf,
                                          int w, int lane) {
#pragma unroll
  for (int i = 0; i < 2; ++i) {
    int slot = (w * 2 + i) * 64 + lane;        // 0..511
    int row = slot >> 3;                       // 0..63 (128B rows)
    int ch = (slot & 7) ^ (row & 7);           // inverse swizzle on global source
    gload16(Kb + (size_t)(kt * 64 + row) * HD_ + ch * 8, klds + buf * 8192 + slot * 16);
    gload16(Vb + (size_t)row * S_ + kt * 64 + ch * 8, klds + 16384 + buf * 8192 + slot * 16);
  }
}

__global__ __launch_bounds__(256, 3) void k_attn(const ushort* __restrict__ Qh,
                                                 const ushort* __restrict__ Kh,
                                                 const ushort* __restrict__ Vh,
                                                 ushort* __restrict__ AOb) {
  __shared__ char klds[32768];     // K dbuf [2][64][64], V^T dbuf [2][64][64]
  const int qt = 15 - (int)(blockIdx.x >> 6);     // heavy tiles first
  const int bh = blockIdx.x & 63;
  const int b = bh >> 5, h = bh & 31, kv = h >> 2;
  const ushort* Qb = Qh + (size_t)(b * H_ + h) * S_ * HD_;
  const ushort* Kb = Kh + (size_t)(b * KV_ + kv) * S_ * HD_;
  const ushort* Vb = Vh + (size_t)(b * KV_ + kv) * HD_ * S_;   // [d][s]
  const int tid = threadIdx.x, lane = tid & 63, w = tid >> 6;
  const int fr = lane & 15, fg = lane >> 4;
  const f32x4 z = {0.f, 0.f, 0.f, 0.f};
  const int qbase = qt * 128 + w * 32;

  short8 qf[2][2];       // B-operand: lane holds Q[q=fr][d=fg*8..]
#pragma unroll
  for (int mi = 0; mi < 2; ++mi) {
    int qrow = qbase + mi * 16 + fr;
#pragma unroll
    for (int dd = 0; dd < 2; ++dd)
      qf[mi][dd] = pack8(*(const uint4*)(Qb + (size_t)qrow * HD_ + dd * 32 + fg * 8));
  }
  f32x4 o[2][4];         // O[q=mi*16+fg*4+r][d=db*16+fr]
  float m_run[2], l_run[2];   // per lane: q = mi*16+fr
#pragma unroll
  for (int mi = 0; mi < 2; ++mi) {
    m_run[mi] = -1e30f; l_run[mi] = 0.f;
#pragma unroll
    for (int db = 0; db < 4; ++db) o[mi][db] = z;
  }

  const int nt = 2 * qt + 2;
  att_stage(Kb, Vb, klds, 0, 0, w, lane);
  __syncthreads();
  int cur = 0;
  for (int kt = 0; kt < nt; ++kt) {
    if (kt + 1 < nt) att_stage(Kb, Vb, klds, kt + 1, cur ^ 1, w, lane);
    const char* kls = klds + cur * 8192;
    const char* vls = klds + 16384 + cur * 8192;

    // S^T = K Q^T : C col=q=fr, row k = kb*16 + fg*4 + r  (log2 domain)
    f32x4 s[2][4];
    __builtin_amdgcn_s_setprio(1);
#pragma unroll
    for (int kb = 0; kb < 4; ++kb) {
      short8 kf0 = ldsw(kls, kb * 16 + fr, fg);
      short8 kf1 = ldsw(kls, kb * 16 + fr, 4 + fg);
#pragma unroll
      for (int mi = 0; mi < 2; ++mi) {
        f32x4 t = __builtin_amdgcn_mfma_f32_16x16x32_bf16(kf0, qf[mi][0], z, 0, 0, 0);
        s[mi][kb] = __builtin_amdgcn_mfma_f32_16x16x32_bf16(kf1, qf[mi][1], t, 0, 0, 0);
      }
    }
    __builtin_amdgcn_s_setprio(0);
    if (kt >= 2 * qt) {                        // diagonal: causal mask
#pragma unroll
      for (int mi = 0; mi < 2; ++mi)
#pragma unroll
        for (int kb = 0; kb < 4; ++kb)
#pragma unroll
          for (int r = 0; r < 4; ++r)
            if (kt * 64 + kb * 16 + fg * 4 + r > qbase + mi * 16 + fr)
              s[mi][kb][r] = -1e30f;
    }

    short8 pa[2][2];     // PV A-operand: P[q=fr][k=kk*32+fg*8..]
#pragma unroll
    for (int mi = 0; mi < 2; ++mi) {
      // row max over lane-local 16 + cross-fg reduce
      float mt = s[mi][0][0];
#pragma unroll
      for (int kb = 0; kb < 4; ++kb)
#pragma unroll
        for (int r = 0; r < 4; ++r) mt = fmaxf(mt, s[mi][kb][r]);
      mt = fmaxf(mt, __shfl_xor(mt, 16));
      mt = fmaxf(mt, __shfl_xor(mt, 32));
      float mn = fmaxf(m_run[mi], mt);
      float sc = exp2fast(m_run[mi] - mn);
      m_run[mi] = mn;
      float su = 0.f;
#pragma unroll
      for (int kb = 0; kb < 4; ++kb)
#pragma unroll
        for (int r = 0; r < 4; ++r) {
          float pv = exp2fast(s[mi][kb][r] - mn);
          s[mi][kb][r] = pv; su += pv;
        }
      su += __shfl_xor(su, 16);
      su += __shfl_xor(su, 32);
      l_run[mi] = l_run[mi] * sc + su;
      // rescale O rows (q = fg*4+r lives on lane with fr = fg*4+r)
#pragma unroll
      for (int r = 0; r < 4; ++r) {
        float scb = __shfl(sc, fg * 16 + fg * 4 + r);
#pragma unroll
        for (int db = 0; db < 4; ++db) o[mi][db][r] *= scb;
      }
      // pack P -> bf16 pairs
      uint P01[4], P23[4];
#pragma unroll
      for (int kb = 0; kb < 4; ++kb) {
        P01[kb] = cvtpk(s[mi][kb][0], s[mi][kb][1]);
        P23[kb] = cvtpk(s[mi][kb][2], s[mi][kb][3]);
      }
      // assemble A-fragments: dword i of pa[kk] = P-pair at k = 32kk + 8fg + 2i.
      // source lane fg_s = (2fg + (i>>1))&3, register kb = 2kk + (fg>>1) -> must
      // select AFTER the shuffle (shfl transmits the SOURCE lane's value).
#pragma unroll
      for (int kk = 0; kk < 2; ++kk) {
        const int s0l = (((2 * fg) & 3) << 4) | fr;       // for i = 0,1
        const int s1l = (((2 * fg + 1) & 3) << 4) | fr;   // for i = 2,3
        uint a0 = (uint)__shfl((int)P01[2 * kk],     s0l);
        uint b0 = (uint)__shfl((int)P01[2 * kk + 1], s0l);
        uint a1 = (uint)__shfl((int)P23[2 * kk],     s0l);
        uint b1 = (uint)__shfl((int)P23[2 * kk + 1], s0l);
        uint a2 = (uint)__shfl((int)P01[2 * kk],     s1l);
        uint b2 = (uint)__shfl((int)P01[2 * kk + 1], s1l);
        uint a3 = (uint)__shfl((int)P23[2 * kk],     s1l);
        uint b3 = (uint)__shfl((int)P23[2 * kk + 1], s1l);
        bool hb = (fg & 2) != 0;                          // kb offset = fg>>1
        pa[mi][kk] = pack8(make_uint4(hb ? b0 : a0, hb ? b1 : a1,
                                      hb ? b2 : a2, hb ? b3 : a3));
      }
    }

    // O += P V : B-operand V[k][d=fr] from V^T rows (k contiguous)
    __builtin_amdgcn_s_setprio(1);
#pragma unroll
    for (int kk = 0; kk < 2; ++kk)
#pragma unroll
      for (int db = 0; db < 4; ++db) {
        short8 vf = ldsw(vls, db * 16 + fr, kk * 4 + fg);
#pragma unroll
        for (int mi = 0; mi < 2; ++mi)
          o[mi][db] = __builtin_amdgcn_mfma_f32_16x16x32_bf16(pa[mi][kk], vf, o[mi][db], 0, 0, 0);
      }
    __builtin_amdgcn_s_setprio(0);
    __syncthreads();   // drains vmcnt(0): next tile staged; protects dbuf
    cur ^= 1;
  }
  // epilogue: normalize rows, write AOb[b*S+q][h*64+d]
#pragma unroll
  for (int mi = 0; mi < 2; ++mi) {
    float linv = 1.f / l_run[mi];
#pragma unroll
    for (int r = 0; r < 4; ++r) {
      float lb = __shfl(linv, fg * 16 + fg * 4 + r);
      int qrow = qbase + mi * 16 + fg * 4 + r;
#pragma unroll
      for (int db = 0; db < 4; ++db)
        AOb[(size_t)(b * S_ + qrow) * E_ + h * HD_ + db * 16 + fr] = f2b(o[mi][db][r] * lb);
    }
  }
}

// ---------------- launch ----------------
extern "C" void kernel_launch(void* const* d_in, const int* in_sizes, int n_in,
                              void* d_out, int out_size, void* d_ws, size_t ws_size,
                              hipStream_t stream) {
  const float* x  = (const float*)d_in[0];
  const float* Wq = (const float*)d_in[1];
  const float* Wk = (const float*)d_in[2];
  const float* Wv = (const float*)d_in[3];
  const float* Wo = (const float*)d_in[4];
  float* out = (float*)d_out;

  char* p = (char*)d_ws;
  ushort* xb  = (ushort*)p; p += (size_t)B_ * S_ * E_ * 2;
  ushort* WqT = (ushort*)p; p += (size_t)E_ * H_ * HD_ * 2;
  ushort* WkT = (ushort*)p; p += (size_t)E_ * KV_ * HD_ * 2;
  ushort* WvT = (ushort*)p; p += (size_t)E_ * KV_ * HD_ * 2;
  ushort* WoT = (ushort*)p; p += (size_t)E_ * E_ * 2;
  ushort* Qhp = (ushort*)p; p += (size_t)B_ * H_ * S_ * HD_ * 2;
  ushort* Khp = (ushort*)p; p += (size_t)B_ * KV_ * S_ * HD_ * 2;
  ushort* Vhp = (ushort*)p; p += (size_t)B_ * KV_ * S_ * HD_ * 2;
  ushort* AOb = (ushort*)p; p += (size_t)B_ * S_ * E_ * 2;

  k_cast<<<2048, 256, 0, stream>>>(x, xb, B_ * S_ * E_ / 8);
  k_transpose<<<dim3(32, 32), 256, 0, stream>>>(Wq, WqT, E_, H_ * HD_);
  k_transpose<<<dim3(8, 32),  256, 0, stream>>>(Wk, WkT, E_, KV_ * HD_);
  k_transpose<<<dim3(8, 32),  256, 0, stream>>>(Wv, WvT, E_, KV_ * HD_);
  k_transpose<<<dim3(32, 32), 256, 0, stream>>>(Wo, WoT, E_, E_);

  k_gemm_qkv<<<dim3(24, 32), 256, 0, stream>>>(xb, WqT, WkT, WvT, Qhp, Khp, Vhp);

  k_attn<<<1024, 256, 0, stream>>>(Qhp, Khp, Vhp, AOb);

  k_gemm_o<<<dim3(16, 32), 256, 0, stream>>>(AOb, WoT, out);
}